// Round 19
// baseline (215.464 us; speedup 1.0000x reference)
//
#include <hip/hip_runtime.h>
#include <hip/hip_bf16.h>

// Router MLP: X[16384,2048] @ W1[2048,1024] -> relu -> @ W2[1024,8] -> softmax -> top2
// R19 = R18 with the spill removed: X reg-loads moved into the staging window
// (issued BEFORE GLB so vmcnt(2) drains them; no registers held across the
// mi-loop). 1024 threads (16 waves 4x4, per-wave 64x64), 256x256x32,
// f16 hi/lo split MFMA, 128KiB LDS dbuf, counted vmcnt(2), XOR-swizzle.
// Outputs (flat f32): logits[16384*8] | weights[16384*2] | indices-as-float[16384*2]

#define HDIM 2048
#define HM 1024
#define NROWS 16384
#define NE 8
#define KSTEPS 64  // 2048 / 32

typedef _Float16 f16;
typedef f16 f16x8 __attribute__((ext_vector_type(8)));
typedef __fp16 h16x2 __attribute__((ext_vector_type(2)));
typedef float f32x4 __attribute__((ext_vector_type(4)));

union frag8 {
  f16x8 v;
  h16x2 p[4];
};

__device__ __forceinline__ void gload16(const void* g, void* l) {
  __builtin_amdgcn_global_load_lds(
      (const __attribute__((address_space(1))) void*)g,
      (__attribute__((address_space(3))) void*)l, 16, 0, 0);
}

// ---- prep: W1 [2048][1024] f32 -> W1s swizzled LDS-image tiles -------------
// W1s[nb][ktidx] = 32KB image: 256 rows (n = nb*256+r) x 8 slots of 16B.
// LDS slot sp holds data slot s = sp^(r&7); s<4: hi f16 of W1[kt+8s..+8][n],
// s>=4: lo f16 (x - (f16)x).
__global__ __launch_bounds__(256) void prep_w1(const float* __restrict__ W1,
                                               f16* __restrict__ W1s) {
  const int nb = blockIdx.x & 3;
  const int ktidx = blockIdx.x >> 2;
  const int r = threadIdx.x;  // 0..255
  const int n = nb * 256 + r;
  const int kt = ktidx * 32;
  f16 hi[32], lo[32];
#pragma unroll
  for (int kk = 0; kk < 32; ++kk) {
    float x = W1[(size_t)(kt + kk) * HM + n];
    f16 h = (f16)x;
    hi[kk] = h;
    lo[kk] = (f16)(x - (float)h);
  }
  f16* dst = W1s + (size_t)(nb * 64 + ktidx) * 16384 + r * 64;
#pragma unroll
  for (int sp = 0; sp < 8; ++sp) {
    int s = sp ^ (r & 7);
    f16x8 v;
#pragma unroll
    for (int j = 0; j < 8; ++j)
      v[j] = (s < 4) ? hi[8 * s + j] : lo[8 * (s - 4) + j];
    *(f16x8*)(dst + sp * 8) = v;
  }
}

// ---- main GEMM: 256x256 tile, BK=32, 16 waves (4x4) ------------------------
__global__ __launch_bounds__(1024) void router_mfma(
    const float* __restrict__ X, const f16* __restrict__ W1s,
    const float* __restrict__ b1, const float* __restrict__ W2,
    float* __restrict__ pl) {
  // XCD swizzle: 256 wgs -> 32 contiguous per XCD; same-rb blocks cluster.
  const int bid = blockIdx.x;
  const int wg = (bid & 7) * 32 + (bid >> 3);
  const int rb = wg >> 2;  // 0..63
  const int nb = wg & 3;   // 0..3

  const int t = threadIdx.x;
  const int lane = t & 63;
  const int wave = t >> 6;       // 0..15
  const int wm = wave >> 2;      // 0..3  (64 rows each)
  const int wn = wave & 3;       // 0..3  (64 cols each)
  const int lane15 = lane & 15;
  const int lgrp = lane >> 4;    // 0..3

  extern __shared__ char smem[];  // [2][65536]: A image 32KB | B image 32KB

  // ---- A reg-staging: thread t owns row t>>2 (0..255), k-octet t&3 ----
  const int srow = t >> 2;
  const int squart = t & 3;  // k-octet index (8 floats each)
  const float* Xr = X + (size_t)(rb * 256 + srow) * HDIM + squart * 8;
  const int sm = srow & 7;
  const int woff_h = srow * 128 + ((squart ^ sm) << 4);
  const int woff_l = srow * 128 + (((4 + squart) ^ sm) << 4);

  const char* W1sB = (const char*)W1s + (size_t)nb * 64 * 32768;
  const int t16 = t * 16;

// issue the 2 B-staging gloads for tile KT into buffer BUF
#define GLB(KT, BUF)                                                      \
  {                                                                       \
    char* bB_ = smem + (BUF) * 65536 + 32768;                             \
    _Pragma("unroll")                                                     \
    for (int i_ = 0; i_ < 2; ++i_)                                        \
      gload16(W1sB + (((size_t)(KT)) << 15) + i_ * 16384 + t16,           \
              bB_ + i_ * 16384 + t16);                                    \
  }

// split 8 regs (x0,x1 float4) and ds_write hi+lo A image slots into BUF
#define SPLITWR(BUF, x0, x1)                                              \
  {                                                                       \
    char* bA_ = smem + (BUF) * 65536;                                     \
    frag8 hi_, lo_;                                                       \
    hi_.p[0] = __builtin_amdgcn_cvt_pkrtz(x0.x, x0.y);                    \
    hi_.p[1] = __builtin_amdgcn_cvt_pkrtz(x0.z, x0.w);                    \
    hi_.p[2] = __builtin_amdgcn_cvt_pkrtz(x1.x, x1.y);                    \
    hi_.p[3] = __builtin_amdgcn_cvt_pkrtz(x1.z, x1.w);                    \
    lo_.p[0] = __builtin_amdgcn_cvt_pkrtz(x0.x - (float)hi_.p[0][0],      \
                                          x0.y - (float)hi_.p[0][1]);     \
    lo_.p[1] = __builtin_amdgcn_cvt_pkrtz(x0.z - (float)hi_.p[1][0],      \
                                          x0.w - (float)hi_.p[1][1]);     \
    lo_.p[2] = __builtin_amdgcn_cvt_pkrtz(x1.x - (float)hi_.p[2][0],      \
                                          x1.y - (float)hi_.p[2][1]);     \
    lo_.p[3] = __builtin_amdgcn_cvt_pkrtz(x1.z - (float)hi_.p[3][0],      \
                                          x1.w - (float)hi_.p[3][1]);     \
    *(f16x8*)(bA_ + woff_h) = hi_.v;                                      \
    *(f16x8*)(bA_ + woff_l) = lo_.v;                                      \
  }

  // A/B frag read constants (mi-independent swizzle since mi*16 % 8 == 0)
  const int arow_base = wm * 64 + lane15;
  const int offAh = ((lgrp ^ (lane15 & 7)) << 4);
  const int offAl = (((4 + lgrp) ^ (lane15 & 7)) << 4);

  f32x4 acc[4][4];
#pragma unroll
  for (int i = 0; i < 4; ++i)
#pragma unroll
    for (int j = 0; j < 4; ++j) acc[i][j] = (f32x4){0.f, 0.f, 0.f, 0.f};

  // ---- prologue: stage tiles 0 (buf0) and 1 (buf1) ----
  {
    GLB(0, 0);
    GLB(1, 1);
    float4 a0 = *(const float4*)(Xr + 0);
    float4 a1 = *(const float4*)(Xr + 4);
    float4 c0 = *(const float4*)(Xr + 32);
    float4 c1 = *(const float4*)(Xr + 36);
    asm volatile("s_waitcnt vmcnt(0)" ::: "memory");
    SPLITWR(0, a0, a1);
    SPLITWR(1, c0, c1);
    asm volatile("s_waitcnt lgkmcnt(0)" ::: "memory");
  }
  __builtin_amdgcn_s_barrier();

  int cur = 0;
#pragma unroll 1
  for (int kti = 0; kti < KSTEPS; ++kti) {
    const char* ldsA = smem + cur * 65536;
    const f16* ldsB = (const f16*)(ldsA + 32768);
    const bool stage2 = (kti + 2 < KSTEPS);

    // B fragments (pre-split hi/lo, swizzled)
    frag8 bh[4], bl[4];
#pragma unroll
    for (int ni = 0; ni < 4; ++ni) {
      int c = wn * 64 + ni * 16 + lane15;
      bh[ni].v = *(const f16x8*)&ldsB[c * 64 + ((lgrp ^ (c & 7)) << 3)];
      bl[ni].v = *(const f16x8*)&ldsB[c * 64 + (((4 + lgrp) ^ (c & 7)) << 3)];
    }

#pragma unroll
    for (int mi = 0; mi < 4; ++mi) {
      frag8 ah, al;
      const char* rowp = ldsA + (arow_base + mi * 16) * 128;
      ah.v = *(const f16x8*)(rowp + offAh);
      al.v = *(const f16x8*)(rowp + offAl);
      __builtin_amdgcn_s_setprio(1);
#pragma unroll
      for (int ni = 0; ni < 4; ++ni) {
        acc[mi][ni] = __builtin_amdgcn_mfma_f32_16x16x32_f16(
            ah.v, bh[ni].v, acc[mi][ni], 0, 0, 0);
        acc[mi][ni] = __builtin_amdgcn_mfma_f32_16x16x32_f16(
            ah.v, bl[ni].v, acc[mi][ni], 0, 0, 0);
        acc[mi][ni] = __builtin_amdgcn_mfma_f32_16x16x32_f16(
            al.v, bh[ni].v, acc[mi][ni], 0, 0, 0);
      }
      __builtin_amdgcn_s_setprio(0);
    }

    if (kti == KSTEPS - 1) break;
    __builtin_amdgcn_sched_barrier(0);
    __builtin_amdgcn_s_barrier();  // #1: all waves done reading smem[cur]
    if (stage2) {
      // x-loads FIRST (short register lifetime: only within this window)
      const float* xs = Xr + (kti + 2) * 32;
      float4 x0 = *(const float4*)(xs + 0);
      float4 x1 = *(const float4*)(xs + 4);
      GLB(kti + 2, cur);  // B(kti+2) in flight across the barrier
      // drain x-loads + B(kti+1) (older), keep B(kti+2) (2 newest) in flight
      asm volatile("s_waitcnt vmcnt(2)" ::: "memory");
      SPLITWR(cur, x0, x1);  // A(kti+2) image into buf cur
      asm volatile("s_waitcnt lgkmcnt(0)" ::: "memory");
    } else {
      asm volatile("s_waitcnt vmcnt(0)" ::: "memory");  // tail drain
    }
    __builtin_amdgcn_s_barrier();  // #2: smem[cur^1] (tile kti+1) ready
    cur ^= 1;
  }

  // ---- fused epilogue: relu(acc+b1) @ W2 chunk, 16-lane reduce ----
  __syncthreads();
  float* red = (float*)smem;  // [4][256][8] f32 = 32KB

  float bvals[4];
  float w2r[4][NE];
#pragma unroll
  for (int ni = 0; ni < 4; ++ni) {
    int c = nb * 256 + wn * 64 + ni * 16 + lane15;
    bvals[ni] = b1[c];
    const float* src = W2 + (size_t)c * NE;
#pragma unroll
    for (int e = 0; e < NE; ++e) w2r[ni][e] = src[e];
  }

#pragma unroll
  for (int mi = 0; mi < 4; ++mi) {
    float plr[4][NE];
#pragma unroll
    for (int j = 0; j < 4; ++j)
#pragma unroll
      for (int e = 0; e < NE; ++e) plr[j][e] = 0.f;
#pragma unroll
    for (int ni = 0; ni < 4; ++ni) {
#pragma unroll
      for (int j = 0; j < 4; ++j) {
        float h = acc[mi][ni][j] + bvals[ni];
        h = fmaxf(h, 0.f);
#pragma unroll
        for (int e = 0; e < NE; ++e) plr[j][e] = fmaf(h, w2r[ni][e], plr[j][e]);
      }
    }
#pragma unroll
    for (int m = 1; m < 16; m <<= 1)
#pragma unroll
      for (int j = 0; j < 4; ++j)
#pragma unroll
        for (int e = 0; e < NE; ++e)
          plr[j][e] += __shfl_xor(plr[j][e], m, 64);
    if (lane15 == 0) {
#pragma unroll
      for (int j = 0; j < 4; ++j) {
        int rr = wm * 64 + mi * 16 + lgrp * 4 + j;
#pragma unroll
        for (int e = 0; e < NE; ++e)
          red[(size_t)wn * 2048 + rr * NE + e] = plr[j][e];
      }
    }
  }
  __syncthreads();
  for (int i = t; i < 256 * NE; i += 1024) {
    int r = i >> 3, e = i & 7;
    int row = rb * 256 + r;
    float s = red[i] + red[2048 + i] + red[4096 + i] + red[6144 + i];
    pl[((size_t)nb * NROWS + row) * NE + e] = s;
  }
}

// ---- finalize: sum partials + b2, softmax, top-2 ----------------------------
__global__ __launch_bounds__(256) void router_finalize(
    const float* __restrict__ pl, const float* __restrict__ b2,
    float* __restrict__ out) {
  int row = blockIdx.x * 256 + threadIdx.x;
  if (row >= NROWS) return;
  float l[NE];
#pragma unroll
  for (int e = 0; e < NE; ++e) l[e] = b2[e];
  for (int nb = 0; nb < 4; ++nb) {
    const float* src = pl + ((size_t)nb * NROWS + row) * NE;
#pragma unroll
    for (int e = 0; e < NE; ++e) l[e] += src[e];
  }
#pragma unroll
  for (int e = 0; e < NE; ++e) out[(size_t)row * NE + e] = l[e];

  float m = l[0];
#pragma unroll
  for (int e = 1; e < NE; ++e) m = fmaxf(m, l[e]);
  float p[NE], s = 0.f;
#pragma unroll
  for (int e = 0; e < NE; ++e) {
    p[e] = expf(l[e] - m);
    s += p[e];
  }
  float inv = 1.f / s;

  float v0 = -1.f, v1 = -1.f;
  int i0 = 0, i1 = 0;
#pragma unroll
  for (int e = 0; e < NE; ++e) {
    float pe = p[e];
    if (pe > v0) {
      v1 = v0; i1 = i0;
      v0 = pe; i0 = e;
    } else if (pe > v1) {
      v1 = pe; i1 = e;
    }
  }
  size_t wbase = (size_t)NROWS * NE + (size_t)row * 2;
  out[wbase] = v0 * inv;
  out[wbase + 1] = v1 * inv;
  size_t ibase = (size_t)NROWS * NE + (size_t)NROWS * 2 + (size_t)row * 2;
  out[ibase] = (float)i0;
  out[ibase + 1] = (float)i1;
}

extern "C" void kernel_launch(void* const* d_in, const int* in_sizes, int n_in,
                              void* d_out, int out_size, void* d_ws,
                              size_t ws_size, hipStream_t stream) {
  const float* X = (const float*)d_in[0];
  const float* W1 = (const float*)d_in[1];
  const float* b1 = (const float*)d_in[2];
  const float* W2 = (const float*)d_in[3];
  const float* b2 = (const float*)d_in[4];
  float* out = (float*)d_out;

  // ws: pl 2MB (at 0) | W1s 8MB (at +4MB)
  float* pl = (float*)d_ws;
  f16* W1s = (f16*)((char*)d_ws + (size_t)4 * 1024 * 1024);

  // allow 128 KiB dynamic LDS (non-stream runtime call; capture-safe)
  (void)hipFuncSetAttribute((const void*)router_mfma,
                            hipFuncAttributeMaxDynamicSharedMemorySize, 131072);

  hipLaunchKernelGGL(prep_w1, dim3(256), dim3(256), 0, stream, W1, W1s);
  hipLaunchKernelGGL(router_mfma, dim3(256), dim3(1024), 131072, stream, X,
                     W1s, b1, W2, pl);
  hipLaunchKernelGGL(router_finalize, dim3(NROWS / 256), dim3(256), 0, stream,
                     pl, b2, out);
}

// Round 20
// 213.062 us; speedup vs baseline: 1.0113x; 1.0113x over previous
//
#include <hip/hip_runtime.h>
#include <hip/hip_bf16.h>

// Router MLP: X[16384,2048] @ W1[2048,1024] -> relu -> @ W2[1024,8] -> softmax -> top2
// R20 = R15 base with SINGLE-barrier K-step: {compute -> vmcnt(0) [drains
// year-old GLB(kti+1), ~free] -> s_barrier -> stage(kti+2) with vmcnt(4) and
// NO trailing barrier}. Fast waves run ahead into compute(kti+1) while slow
// waves stage -> de-lockstepped stage/compute overlap. 2-deep staging makes
// this race-free (tile k+1 published by barrier k; buf freed by barrier k).
// f16 hi/lo split MFMA (Xh@Wh + Xh@Wl + Xl@Wh), 256x256x32, 8 waves,
// 128KiB LDS dbuf, XOR-swizzled images.
// Outputs (flat f32): logits[16384*8] | weights[16384*2] | indices-as-float[16384*2]

#define HDIM 2048
#define HM 1024
#define NROWS 16384
#define NE 8
#define KSTEPS 64  // 2048 / 32

typedef _Float16 f16;
typedef f16 f16x8 __attribute__((ext_vector_type(8)));
typedef __fp16 h16x2 __attribute__((ext_vector_type(2)));
typedef float f32x4 __attribute__((ext_vector_type(4)));

union frag8 {
  f16x8 v;
  h16x2 p[4];
};

__device__ __forceinline__ void gload16(const void* g, void* l) {
  __builtin_amdgcn_global_load_lds(
      (const __attribute__((address_space(1))) void*)g,
      (__attribute__((address_space(3))) void*)l, 16, 0, 0);
}

// ---- prep: W1 [2048][1024] f32 -> W1s swizzled LDS-image tiles -------------
// W1s[nb][ktidx] = 32KB image: 256 rows (n = nb*256+r) x 8 slots of 16B.
// LDS slot sp holds data slot s = sp^(r&7); s<4: hi f16 of W1[kt+8s..+8][n],
// s>=4: lo f16 (x - (f16)x).
__global__ __launch_bounds__(256) void prep_w1(const float* __restrict__ W1,
                                               f16* __restrict__ W1s) {
  const int nb = blockIdx.x & 3;
  const int ktidx = blockIdx.x >> 2;
  const int r = threadIdx.x;  // 0..255
  const int n = nb * 256 + r;
  const int kt = ktidx * 32;
  f16 hi[32], lo[32];
#pragma unroll
  for (int kk = 0; kk < 32; ++kk) {
    float x = W1[(size_t)(kt + kk) * HM + n];
    f16 h = (f16)x;
    hi[kk] = h;
    lo[kk] = (f16)(x - (float)h);
  }
  f16* dst = W1s + (size_t)(nb * 64 + ktidx) * 16384 + r * 64;
#pragma unroll
  for (int sp = 0; sp < 8; ++sp) {
    int s = sp ^ (r & 7);
    f16x8 v;
#pragma unroll
    for (int j = 0; j < 8; ++j)
      v[j] = (s < 4) ? hi[8 * s + j] : lo[8 * (s - 4) + j];
    *(f16x8*)(dst + sp * 8) = v;
  }
}

// ---- main GEMM: 256x256 tile, BK=32, 8 waves (2x4), 1 barrier/K-step -------
__global__ __launch_bounds__(512, 2) void router_mfma(
    const float* __restrict__ X, const f16* __restrict__ W1s,
    const float* __restrict__ b1, const float* __restrict__ W2,
    float* __restrict__ pl) {
  // XCD swizzle: 256 wgs -> 32 contiguous per XCD; same-rb blocks cluster.
  const int bid = blockIdx.x;
  const int wg = (bid & 7) * 32 + (bid >> 3);
  const int rb = wg >> 2;  // 0..63
  const int nb = wg & 3;   // 0..3

  const int t = threadIdx.x;
  const int lane = t & 63;
  const int wave = t >> 6;       // 0..7
  const int wm = wave >> 2;      // 0..1  (128 rows each)
  const int wn = wave & 3;       // 0..3  (64 cols each)
  const int lane15 = lane & 15;
  const int lgrp = lane >> 4;    // 0..3

  extern __shared__ char smem[];  // [2][65536]: A image 32KB | B image 32KB

  // ---- A reg-staging: thread t owns row t>>1 (0..255), k-half t&1 ----
  const int srow = t >> 1;
  const int shalf = t & 1;
  const float* Xr = X + (size_t)(rb * 256 + srow) * HDIM + shalf * 16;
  const int sm = srow & 7;
  const int woff_h0 = srow * 128 + (((2 * shalf) ^ sm) << 4);
  const int woff_h1 = srow * 128 + (((2 * shalf + 1) ^ sm) << 4);
  const int woff_l0 = srow * 128 + (((4 + 2 * shalf) ^ sm) << 4);
  const int woff_l1 = srow * 128 + (((5 + 2 * shalf) ^ sm) << 4);

  const char* W1sB = (const char*)W1s + (size_t)nb * 64 * 32768;
  const int t16 = t * 16;

// issue the 4 B-staging gloads for tile KT into buffer BUF
#define GLB(KT, BUF)                                                      \
  {                                                                       \
    char* bB_ = smem + (BUF) * 65536 + 32768;                             \
    _Pragma("unroll")                                                     \
    for (int i_ = 0; i_ < 4; ++i_)                                        \
      gload16(W1sB + (((size_t)(KT)) << 15) + i_ * 8192 + t16,            \
              bB_ + i_ * 8192 + t16);                                     \
  }

// split 16 regs (x0..x3 float4) and ds_write the A image rows into BUF
#define SPLITWR(BUF, x0, x1, x2, x3)                                      \
  {                                                                       \
    char* bA_ = smem + (BUF) * 65536;                                     \
    frag8 hi0_, hi1_, lo0_, lo1_;                                         \
    hi0_.p[0] = __builtin_amdgcn_cvt_pkrtz(x0.x, x0.y);                   \
    hi0_.p[1] = __builtin_amdgcn_cvt_pkrtz(x0.z, x0.w);                   \
    hi0_.p[2] = __builtin_amdgcn_cvt_pkrtz(x1.x, x1.y);                   \
    hi0_.p[3] = __builtin_amdgcn_cvt_pkrtz(x1.z, x1.w);                   \
    hi1_.p[0] = __builtin_amdgcn_cvt_pkrtz(x2.x, x2.y);                   \
    hi1_.p[1] = __builtin_amdgcn_cvt_pkrtz(x2.z, x2.w);                   \
    hi1_.p[2] = __builtin_amdgcn_cvt_pkrtz(x3.x, x3.y);                   \
    hi1_.p[3] = __builtin_amdgcn_cvt_pkrtz(x3.z, x3.w);                   \
    lo0_.p[0] = __builtin_amdgcn_cvt_pkrtz(x0.x - (float)hi0_.p[0][0],    \
                                           x0.y - (float)hi0_.p[0][1]);   \
    lo0_.p[1] = __builtin_amdgcn_cvt_pkrtz(x0.z - (float)hi0_.p[1][0],    \
                                           x0.w - (float)hi0_.p[1][1]);   \
    lo0_.p[2] = __builtin_amdgcn_cvt_pkrtz(x1.x - (float)hi0_.p[2][0],    \
                                           x1.y - (float)hi0_.p[2][1]);   \
    lo0_.p[3] = __builtin_amdgcn_cvt_pkrtz(x1.z - (float)hi0_.p[3][0],    \
                                           x1.w - (float)hi0_.p[3][1]);   \
    lo1_.p[0] = __builtin_amdgcn_cvt_pkrtz(x2.x - (float)hi1_.p[0][0],    \
                                           x2.y - (float)hi1_.p[0][1]);   \
    lo1_.p[1] = __builtin_amdgcn_cvt_pkrtz(x2.z - (float)hi1_.p[1][0],    \
                                           x2.w - (float)hi1_.p[1][1]);   \
    lo1_.p[2] = __builtin_amdgcn_cvt_pkrtz(x3.x - (float)hi1_.p[2][0],    \
                                           x3.y - (float)hi1_.p[2][1]);   \
    lo1_.p[3] = __builtin_amdgcn_cvt_pkrtz(x3.z - (float)hi1_.p[3][0],    \
                                           x3.w - (float)hi1_.p[3][1]);   \
    *(f16x8*)(bA_ + woff_h0) = hi0_.v;                                    \
    *(f16x8*)(bA_ + woff_h1) = hi1_.v;                                    \
    *(f16x8*)(bA_ + woff_l0) = lo0_.v;                                    \
    *(f16x8*)(bA_ + woff_l1) = lo1_.v;                                    \
  }

  f32x4 acc[8][4];
#pragma unroll
  for (int i = 0; i < 8; ++i)
#pragma unroll
    for (int j = 0; j < 4; ++j) acc[i][j] = (f32x4){0.f, 0.f, 0.f, 0.f};

  // ---- prologue: stage tiles 0 (buf0) and 1 (buf1) ----
  {
    GLB(0, 0);
    GLB(1, 1);
    float4 a0 = *(const float4*)(Xr + 0);
    float4 a1 = *(const float4*)(Xr + 4);
    float4 a2 = *(const float4*)(Xr + 8);
    float4 a3 = *(const float4*)(Xr + 12);
    float4 c0 = *(const float4*)(Xr + 32);
    float4 c1 = *(const float4*)(Xr + 36);
    float4 c2 = *(const float4*)(Xr + 40);
    float4 c3 = *(const float4*)(Xr + 44);
    asm volatile("s_waitcnt vmcnt(0)" ::: "memory");
    SPLITWR(0, a0, a1, a2, a3);
    SPLITWR(1, c0, c1, c2, c3);
    asm volatile("s_waitcnt lgkmcnt(0)" ::: "memory");
  }
  __builtin_amdgcn_s_barrier();

  // A frag read constants (mi-independent swizzle since mi*16 % 8 == 0)
  const int arow_base = wm * 128 + lane15;
  const int offAh = ((lgrp ^ (lane15 & 7)) << 4);
  const int offAl = (((4 + lgrp) ^ (lane15 & 7)) << 4);

  int cur = 0;
#pragma unroll 1
  for (int kti = 0; kti < KSTEPS; ++kti) {
    const char* ldsA = smem + cur * 65536;
    const f16* ldsB = (const f16*)(ldsA + 32768);
    const bool stage2 = (kti + 2 < KSTEPS);

    // B fragments (pre-split hi/lo, swizzled)
    frag8 bh[4], bl[4];
#pragma unroll
    for (int ni = 0; ni < 4; ++ni) {
      int c = wn * 64 + ni * 16 + lane15;
      bh[ni].v = *(const f16x8*)&ldsB[c * 64 + ((lgrp ^ (c & 7)) << 3)];
      bl[ni].v = *(const f16x8*)&ldsB[c * 64 + (((4 + lgrp) ^ (c & 7)) << 3)];
    }

    // rolling one-ahead A frag reads (pure f16 b128, no split)
    frag8 ah, al, nah, nal;
    {
      const char* rowp = ldsA + arow_base * 128;
      ah.v = *(const f16x8*)(rowp + offAh);
      al.v = *(const f16x8*)(rowp + offAl);
    }
#pragma unroll
    for (int mi = 0; mi < 8; ++mi) {
      if (mi < 7) {
        const char* rowp = ldsA + (arow_base + (mi + 1) * 16) * 128;
        nah.v = *(const f16x8*)(rowp + offAh);
        nal.v = *(const f16x8*)(rowp + offAl);
      }
      __builtin_amdgcn_s_setprio(1);
#pragma unroll
      for (int ni = 0; ni < 4; ++ni) {
        acc[mi][ni] = __builtin_amdgcn_mfma_f32_16x16x32_f16(
            ah.v, bh[ni].v, acc[mi][ni], 0, 0, 0);
        acc[mi][ni] = __builtin_amdgcn_mfma_f32_16x16x32_f16(
            ah.v, bl[ni].v, acc[mi][ni], 0, 0, 0);
        acc[mi][ni] = __builtin_amdgcn_mfma_f32_16x16x32_f16(
            al.v, bh[ni].v, acc[mi][ni], 0, 0, 0);
      }
      __builtin_amdgcn_s_setprio(0);
      ah = nah;
      al = nal;
    }

    if (kti == KSTEPS - 1) break;
    __builtin_amdgcn_sched_barrier(0);
    // drain GLB(kti+1) (issued a full iteration ago -> already landed, ~free)
    asm volatile("s_waitcnt vmcnt(0)" ::: "memory");
    __builtin_amdgcn_s_barrier();  // SINGLE barrier: frees buf[cur] for
                                   // overwrite AND publishes tile kti+1
    if (stage2) {
      // x-loads first (short lifetime), then B gloads for kti+2
      const float* xs = Xr + (kti + 2) * 32;
      float4 x0 = *(const float4*)(xs + 0);
      float4 x1 = *(const float4*)(xs + 4);
      float4 x2 = *(const float4*)(xs + 8);
      float4 x3 = *(const float4*)(xs + 12);
      GLB(kti + 2, cur);
      // drain x-loads (4 oldest), keep GLB(kti+2) (4 newest) in flight
      asm volatile("s_waitcnt vmcnt(4)" ::: "memory");
      SPLITWR(cur, x0, x1, x2, x3);  // A(kti+2) image into buf cur
      asm volatile("s_waitcnt lgkmcnt(0)" ::: "memory");
      // NO trailing barrier: proceed straight into compute(kti+1)
    }
    cur ^= 1;
  }

  // ---- fused epilogue: relu(acc+b1) @ W2 chunk, 16-lane reduce ----
  __syncthreads();
  float* red = (float*)smem;  // [4][256][8] f32 = 32KB

  float bvals[4];
  float w2r[4][NE];
#pragma unroll
  for (int ni = 0; ni < 4; ++ni) {
    int c = nb * 256 + wn * 64 + ni * 16 + lane15;
    bvals[ni] = b1[c];
    const float* src = W2 + (size_t)c * NE;
#pragma unroll
    for (int e = 0; e < NE; ++e) w2r[ni][e] = src[e];
  }

#pragma unroll
  for (int mi = 0; mi < 8; ++mi) {
    float plr[4][NE];
#pragma unroll
    for (int j = 0; j < 4; ++j)
#pragma unroll
      for (int e = 0; e < NE; ++e) plr[j][e] = 0.f;
#pragma unroll
    for (int ni = 0; ni < 4; ++ni) {
#pragma unroll
      for (int j = 0; j < 4; ++j) {
        float h = acc[mi][ni][j] + bvals[ni];
        h = fmaxf(h, 0.f);
#pragma unroll
        for (int e = 0; e < NE; ++e) plr[j][e] = fmaf(h, w2r[ni][e], plr[j][e]);
      }
    }
#pragma unroll
    for (int m = 1; m < 16; m <<= 1)
#pragma unroll
      for (int j = 0; j < 4; ++j)
#pragma unroll
        for (int e = 0; e < NE; ++e)
          plr[j][e] += __shfl_xor(plr[j][e], m, 64);
    if (lane15 == 0) {
#pragma unroll
      for (int j = 0; j < 4; ++j) {
        int rr = wm * 128 + mi * 16 + lgrp * 4 + j;
#pragma unroll
        for (int e = 0; e < NE; ++e)
          red[(size_t)wn * 2048 + rr * NE + e] = plr[j][e];
      }
    }
  }
  __syncthreads();
  for (int i = t; i < 256 * NE; i += 512) {
    int r = i >> 3, e = i & 7;
    int row = rb * 256 + r;
    float s = red[i] + red[2048 + i] + red[4096 + i] + red[6144 + i];
    pl[((size_t)nb * NROWS + row) * NE + e] = s;
  }
}

// ---- finalize: sum partials + b2, softmax, top-2 ----------------------------
__global__ __launch_bounds__(256) void router_finalize(
    const float* __restrict__ pl, const float* __restrict__ b2,
    float* __restrict__ out) {
  int row = blockIdx.x * 256 + threadIdx.x;
  if (row >= NROWS) return;
  float l[NE];
#pragma unroll
  for (int e = 0; e < NE; ++e) l[e] = b2[e];
  for (int nb = 0; nb < 4; ++nb) {
    const float* src = pl + ((size_t)nb * NROWS + row) * NE;
#pragma unroll
    for (int e = 0; e < NE; ++e) l[e] += src[e];
  }
#pragma unroll
  for (int e = 0; e < NE; ++e) out[(size_t)row * NE + e] = l[e];

  float m = l[0];
#pragma unroll
  for (int e = 1; e < NE; ++e) m = fmaxf(m, l[e]);
  float p[NE], s = 0.f;
#pragma unroll
  for (int e = 0; e < NE; ++e) {
    p[e] = expf(l[e] - m);
    s += p[e];
  }
  float inv = 1.f / s;

  float v0 = -1.f, v1 = -1.f;
  int i0 = 0, i1 = 0;
#pragma unroll
  for (int e = 0; e < NE; ++e) {
    float pe = p[e];
    if (pe > v0) {
      v1 = v0; i1 = i0;
      v0 = pe; i0 = e;
    } else if (pe > v1) {
      v1 = pe; i1 = e;
    }
  }
  size_t wbase = (size_t)NROWS * NE + (size_t)row * 2;
  out[wbase] = v0 * inv;
  out[wbase + 1] = v1 * inv;
  size_t ibase = (size_t)NROWS * NE + (size_t)NROWS * 2 + (size_t)row * 2;
  out[ibase] = (float)i0;
  out[ibase + 1] = (float)i1;
}

extern "C" void kernel_launch(void* const* d_in, const int* in_sizes, int n_in,
                              void* d_out, int out_size, void* d_ws,
                              size_t ws_size, hipStream_t stream) {
  const float* X = (const float*)d_in[0];
  const float* W1 = (const float*)d_in[1];
  const float* b1 = (const float*)d_in[2];
  const float* W2 = (const float*)d_in[3];
  const float* b2 = (const float*)d_in[4];
  float* out = (float*)d_out;

  // ws: pl 2MB (at 0) | W1s 8MB (at +4MB)
  float* pl = (float*)d_ws;
  f16* W1s = (f16*)((char*)d_ws + (size_t)4 * 1024 * 1024);

  // allow 128 KiB dynamic LDS (non-stream runtime call; capture-safe)
  (void)hipFuncSetAttribute((const void*)router_mfma,
                            hipFuncAttributeMaxDynamicSharedMemorySize, 131072);

  hipLaunchKernelGGL(prep_w1, dim3(256), dim3(256), 0, stream, W1, W1s);
  hipLaunchKernelGGL(router_mfma, dim3(256), dim3(512), 131072, stream, X, W1s,
                     b1, W2, pl);
  hipLaunchKernelGGL(router_finalize, dim3(NROWS / 256), dim3(256), 0, stream,
                     pl, b2, out);
}

// Round 21
// 202.403 us; speedup vs baseline: 1.0645x; 1.0527x over previous
//
#include <hip/hip_runtime.h>
#include <hip/hip_bf16.h>

// Router MLP: X[16384,2048] @ W1[2048,1024] -> relu -> @ W2[1024,8] -> softmax -> top2
// FINAL (= R16, best measured 203.5 us): f16 hi/lo split MFMA
// (Xh@Wh + Xh@Wl + Xl@Wh -> fp32-class logits -> exact top-2 indices),
// 256x256x32 tile, 8 waves, 128KiB LDS dbuf, counted vmcnt(4),
// XOR-swizzled A/B LDS images, A reg-staged + split once per block,
// B pre-split+pre-swizzled via global_load_lds, frag pre-read in the
// staging window, fused ReLU+W2 epilogue, XCD-aware block swizzle.
// Outputs (flat f32): logits[16384*8] | weights[16384*2] | indices-as-float[16384*2]

#define HDIM 2048
#define HM 1024
#define NROWS 16384
#define NE 8
#define KSTEPS 64  // 2048 / 32

typedef _Float16 f16;
typedef f16 f16x8 __attribute__((ext_vector_type(8)));
typedef __fp16 h16x2 __attribute__((ext_vector_type(2)));
typedef float f32x4 __attribute__((ext_vector_type(4)));

union frag8 {
  f16x8 v;
  h16x2 p[4];
};

__device__ __forceinline__ void gload16(const void* g, void* l) {
  __builtin_amdgcn_global_load_lds(
      (const __attribute__((address_space(1))) void*)g,
      (__attribute__((address_space(3))) void*)l, 16, 0, 0);
}

// ---- prep: W1 [2048][1024] f32 -> W1s swizzled LDS-image tiles -------------
// W1s[nb][ktidx] = 32KB image: 256 rows (n = nb*256+r) x 8 slots of 16B.
// LDS slot sp holds data slot s = sp^(r&7); s<4: hi f16 of W1[kt+8s..+8][n],
// s>=4: lo f16 (x - (f16)x).
__global__ __launch_bounds__(256) void prep_w1(const float* __restrict__ W1,
                                               f16* __restrict__ W1s) {
  const int nb = blockIdx.x & 3;
  const int ktidx = blockIdx.x >> 2;
  const int r = threadIdx.x;  // 0..255
  const int n = nb * 256 + r;
  const int kt = ktidx * 32;
  f16 hi[32], lo[32];
#pragma unroll
  for (int kk = 0; kk < 32; ++kk) {
    float x = W1[(size_t)(kt + kk) * HM + n];
    f16 h = (f16)x;
    hi[kk] = h;
    lo[kk] = (f16)(x - (float)h);
  }
  f16* dst = W1s + (size_t)(nb * 64 + ktidx) * 16384 + r * 64;
#pragma unroll
  for (int sp = 0; sp < 8; ++sp) {
    int s = sp ^ (r & 7);
    f16x8 v;
#pragma unroll
    for (int j = 0; j < 8; ++j)
      v[j] = (s < 4) ? hi[8 * s + j] : lo[8 * (s - 4) + j];
    *(f16x8*)(dst + sp * 8) = v;
  }
}

// ---- main GEMM: 256x256 tile, BK=32, 8 waves (2x4) -------------------------
__global__ __launch_bounds__(512, 2) void router_mfma(
    const float* __restrict__ X, const f16* __restrict__ W1s,
    const float* __restrict__ b1, const float* __restrict__ W2,
    float* __restrict__ pl) {
  // XCD swizzle: 256 wgs -> 32 contiguous per XCD; same-rb blocks cluster.
  const int bid = blockIdx.x;
  const int wg = (bid & 7) * 32 + (bid >> 3);
  const int rb = wg >> 2;  // 0..63
  const int nb = wg & 3;   // 0..3

  const int t = threadIdx.x;
  const int lane = t & 63;
  const int wave = t >> 6;       // 0..7
  const int wm = wave >> 2;      // 0..1  (128 rows each)
  const int wn = wave & 3;       // 0..3  (64 cols each)
  const int lane15 = lane & 15;
  const int lgrp = lane >> 4;    // 0..3

  extern __shared__ char smem[];  // [2][65536]: A image 32KB | B image 32KB

  // ---- A reg-staging: thread t owns row t>>1 (0..255), k-half t&1 ----
  const int srow = t >> 1;
  const int shalf = t & 1;
  const float* Xr = X + (size_t)(rb * 256 + srow) * HDIM + shalf * 16;
  const int sm = srow & 7;
  const int woff_h0 = srow * 128 + (((2 * shalf) ^ sm) << 4);
  const int woff_h1 = srow * 128 + (((2 * shalf + 1) ^ sm) << 4);
  const int woff_l0 = srow * 128 + (((4 + 2 * shalf) ^ sm) << 4);
  const int woff_l1 = srow * 128 + (((5 + 2 * shalf) ^ sm) << 4);

  const char* W1sB = (const char*)W1s + (size_t)nb * 64 * 32768;
  const int t16 = t * 16;

// issue the 4 B-staging gloads for tile KT into buffer BUF
#define GLB(KT, BUF)                                                      \
  {                                                                       \
    char* bB_ = smem + (BUF) * 65536 + 32768;                             \
    _Pragma("unroll")                                                     \
    for (int i_ = 0; i_ < 4; ++i_)                                        \
      gload16(W1sB + (((size_t)(KT)) << 15) + i_ * 8192 + t16,            \
              bB_ + i_ * 8192 + t16);                                     \
  }

// split 16 regs (x0..x3 float4) and ds_write the A image rows into BUF
#define SPLITWR(BUF, x0, x1, x2, x3)                                      \
  {                                                                       \
    char* bA_ = smem + (BUF) * 65536;                                     \
    frag8 hi0_, hi1_, lo0_, lo1_;                                         \
    hi0_.p[0] = __builtin_amdgcn_cvt_pkrtz(x0.x, x0.y);                   \
    hi0_.p[1] = __builtin_amdgcn_cvt_pkrtz(x0.z, x0.w);                   \
    hi0_.p[2] = __builtin_amdgcn_cvt_pkrtz(x1.x, x1.y);                   \
    hi0_.p[3] = __builtin_amdgcn_cvt_pkrtz(x1.z, x1.w);                   \
    hi1_.p[0] = __builtin_amdgcn_cvt_pkrtz(x2.x, x2.y);                   \
    hi1_.p[1] = __builtin_amdgcn_cvt_pkrtz(x2.z, x2.w);                   \
    hi1_.p[2] = __builtin_amdgcn_cvt_pkrtz(x3.x, x3.y);                   \
    hi1_.p[3] = __builtin_amdgcn_cvt_pkrtz(x3.z, x3.w);                   \
    lo0_.p[0] = __builtin_amdgcn_cvt_pkrtz(x0.x - (float)hi0_.p[0][0],    \
                                           x0.y - (float)hi0_.p[0][1]);   \
    lo0_.p[1] = __builtin_amdgcn_cvt_pkrtz(x0.z - (float)hi0_.p[1][0],    \
                                           x0.w - (float)hi0_.p[1][1]);   \
    lo0_.p[2] = __builtin_amdgcn_cvt_pkrtz(x1.x - (float)hi0_.p[2][0],    \
                                           x1.y - (float)hi0_.p[2][1]);   \
    lo0_.p[3] = __builtin_amdgcn_cvt_pkrtz(x1.z - (float)hi0_.p[3][0],    \
                                           x1.w - (float)hi0_.p[3][1]);   \
    lo1_.p[0] = __builtin_amdgcn_cvt_pkrtz(x2.x - (float)hi1_.p[0][0],    \
                                           x2.y - (float)hi1_.p[0][1]);   \
    lo1_.p[1] = __builtin_amdgcn_cvt_pkrtz(x2.z - (float)hi1_.p[1][0],    \
                                           x2.w - (float)hi1_.p[1][1]);   \
    lo1_.p[2] = __builtin_amdgcn_cvt_pkrtz(x3.x - (float)hi1_.p[2][0],    \
                                           x3.y - (float)hi1_.p[2][1]);   \
    lo1_.p[3] = __builtin_amdgcn_cvt_pkrtz(x3.z - (float)hi1_.p[3][0],    \
                                           x3.w - (float)hi1_.p[3][1]);   \
    *(f16x8*)(bA_ + woff_h0) = hi0_.v;                                    \
    *(f16x8*)(bA_ + woff_h1) = hi1_.v;                                    \
    *(f16x8*)(bA_ + woff_l0) = lo0_.v;                                    \
    *(f16x8*)(bA_ + woff_l1) = lo1_.v;                                    \
  }

  // A frag read constants (mi-independent swizzle since mi*16 % 8 == 0)
  const int arow_base = wm * 128 + lane15;
  const int offAh = ((lgrp ^ (lane15 & 7)) << 4);
  const int offAl = (((4 + lgrp) ^ (lane15 & 7)) << 4);

// pre-read tile frags (all B + A pair0) from buffer BUF into bh/bl/a0h/a0l
#define PREREAD(BUF)                                                      \
  {                                                                       \
    const char* ldsA_ = smem + (BUF) * 65536;                             \
    const f16* ldsB_ = (const f16*)(ldsA_ + 32768);                       \
    _Pragma("unroll")                                                     \
    for (int ni_ = 0; ni_ < 4; ++ni_) {                                   \
      int c_ = wn * 64 + ni_ * 16 + lane15;                               \
      bh[ni_].v = *(const f16x8*)&ldsB_[c_ * 64 + ((lgrp ^ (c_ & 7)) << 3)]; \
      bl[ni_].v =                                                         \
          *(const f16x8*)&ldsB_[c_ * 64 + (((4 + lgrp) ^ (c_ & 7)) << 3)]; \
    }                                                                     \
    const char* rowp_ = ldsA_ + arow_base * 128;                          \
    a0h.v = *(const f16x8*)(rowp_ + offAh);                               \
    a0l.v = *(const f16x8*)(rowp_ + offAl);                               \
  }

  f32x4 acc[8][4];
#pragma unroll
  for (int i = 0; i < 8; ++i)
#pragma unroll
    for (int j = 0; j < 4; ++j) acc[i][j] = (f32x4){0.f, 0.f, 0.f, 0.f};

  // persistent pre-read fragments (tile kti's, loaded at kti-1's window)
  frag8 bh[4], bl[4], a0h, a0l;

  // ---- prologue: stage tiles 0 (buf0) and 1 (buf1); pre-read tile 0 ----
  {
    GLB(0, 0);
    GLB(1, 1);
    float4 a0 = *(const float4*)(Xr + 0);
    float4 a1 = *(const float4*)(Xr + 4);
    float4 a2 = *(const float4*)(Xr + 8);
    float4 a3 = *(const float4*)(Xr + 12);
    float4 c0 = *(const float4*)(Xr + 32);
    float4 c1 = *(const float4*)(Xr + 36);
    float4 c2 = *(const float4*)(Xr + 40);
    float4 c3 = *(const float4*)(Xr + 44);
    asm volatile("s_waitcnt vmcnt(0)" ::: "memory");
    SPLITWR(0, a0, a1, a2, a3);
    SPLITWR(1, c0, c1, c2, c3);
    asm volatile("s_waitcnt lgkmcnt(0)" ::: "memory");
  }
  __builtin_amdgcn_s_barrier();
  PREREAD(0);

  int cur = 0;
#pragma unroll 1
  for (int kti = 0; kti < KSTEPS; ++kti) {
    const char* ldsA = smem + cur * 65536;
    const bool stage2 = (kti + 2 < KSTEPS);

    // issue X reg-loads for tile kti+2 (latency hidden under this tile's MFMA)
    float4 x0, x1, x2, x3;
    if (stage2) {
      const float* xs = Xr + (kti + 2) * 32;
      x0 = *(const float4*)(xs + 0);
      x1 = *(const float4*)(xs + 4);
      x2 = *(const float4*)(xs + 8);
      x3 = *(const float4*)(xs + 12);
    }

    // mi-loop: pair0 pre-read at last window; rolling one-ahead for 1..7
    frag8 ah = a0h, al = a0l, nah, nal;
#pragma unroll
    for (int mi = 0; mi < 8; ++mi) {
      if (mi < 7) {
        const char* rowp = ldsA + (arow_base + (mi + 1) * 16) * 128;
        nah.v = *(const f16x8*)(rowp + offAh);
        nal.v = *(const f16x8*)(rowp + offAl);
      }
      __builtin_amdgcn_s_setprio(1);
#pragma unroll
      for (int ni = 0; ni < 4; ++ni) {
        acc[mi][ni] = __builtin_amdgcn_mfma_f32_16x16x32_f16(
            ah.v, bh[ni].v, acc[mi][ni], 0, 0, 0);
        acc[mi][ni] = __builtin_amdgcn_mfma_f32_16x16x32_f16(
            ah.v, bl[ni].v, acc[mi][ni], 0, 0, 0);
        acc[mi][ni] = __builtin_amdgcn_mfma_f32_16x16x32_f16(
            al.v, bh[ni].v, acc[mi][ni], 0, 0, 0);
      }
      __builtin_amdgcn_s_setprio(0);
      ah = nah;
      al = nal;
    }

    if (kti == KSTEPS - 1) break;
    __builtin_amdgcn_sched_barrier(0);
    __builtin_amdgcn_s_barrier();  // #1: all waves done reading smem[cur]
    if (stage2) {
      GLB(kti + 2, cur);  // B(kti+2) in flight across the barriers
      // drain B(kti+1) + X regs (8 oldest), keep B(kti+2) (4 newest) in flight
      asm volatile("s_waitcnt vmcnt(4)" ::: "memory");
    } else {
      asm volatile("s_waitcnt vmcnt(0)" ::: "memory");  // tail drain
    }
    __builtin_amdgcn_s_barrier();  // #mid: B(kti+1) image visible to all waves
    PREREAD(cur ^ 1);              // tile kti+1 frags, overlapping SPLITWR
    if (stage2) {
      SPLITWR(cur, x0, x1, x2, x3);  // A(kti+2) image into buf cur
    }
    asm volatile("s_waitcnt lgkmcnt(0)" ::: "memory");
    __builtin_amdgcn_s_barrier();  // #2: A(kti+2) written; pre-reads done
    cur ^= 1;
  }

  // ---- fused epilogue: relu(acc+b1) @ W2 chunk, 16-lane reduce ----
  __syncthreads();
  float* red = (float*)smem;  // [4][256][8] f32 = 32KB

  float bvals[4];
  float w2r[4][NE];
#pragma unroll
  for (int ni = 0; ni < 4; ++ni) {
    int c = nb * 256 + wn * 64 + ni * 16 + lane15;
    bvals[ni] = b1[c];
    const float* src = W2 + (size_t)c * NE;
#pragma unroll
    for (int e = 0; e < NE; ++e) w2r[ni][e] = src[e];
  }

#pragma unroll
  for (int mi = 0; mi < 8; ++mi) {
    float plr[4][NE];
#pragma unroll
    for (int j = 0; j < 4; ++j)
#pragma unroll
      for (int e = 0; e < NE; ++e) plr[j][e] = 0.f;
#pragma unroll
    for (int ni = 0; ni < 4; ++ni) {
#pragma unroll
      for (int j = 0; j < 4; ++j) {
        float h = acc[mi][ni][j] + bvals[ni];
        h = fmaxf(h, 0.f);
#pragma unroll
        for (int e = 0; e < NE; ++e) plr[j][e] = fmaf(h, w2r[ni][e], plr[j][e]);
      }
    }
#pragma unroll
    for (int m = 1; m < 16; m <<= 1)
#pragma unroll
      for (int j = 0; j < 4; ++j)
#pragma unroll
        for (int e = 0; e < NE; ++e)
          plr[j][e] += __shfl_xor(plr[j][e], m, 64);
    if (lane15 == 0) {
#pragma unroll
      for (int j = 0; j < 4; ++j) {
        int rr = wm * 128 + mi * 16 + lgrp * 4 + j;
#pragma unroll
        for (int e = 0; e < NE; ++e)
          red[(size_t)wn * 2048 + rr * NE + e] = plr[j][e];
      }
    }
  }
  __syncthreads();
  for (int i = t; i < 256 * NE; i += 512) {
    int r = i >> 3, e = i & 7;
    int row = rb * 256 + r;
    float s = red[i] + red[2048 + i] + red[4096 + i] + red[6144 + i];
    pl[((size_t)nb * NROWS + row) * NE + e] = s;
  }
}

// ---- finalize: sum partials + b2, softmax, top-2 ----------------------------
__global__ __launch_bounds__(256) void router_finalize(
    const float* __restrict__ pl, const float* __restrict__ b2,
    float* __restrict__ out) {
  int row = blockIdx.x * 256 + threadIdx.x;
  if (row >= NROWS) return;
  float l[NE];
#pragma unroll
  for (int e = 0; e < NE; ++e) l[e] = b2[e];
  for (int nb = 0; nb < 4; ++nb) {
    const float* src = pl + ((size_t)nb * NROWS + row) * NE;
#pragma unroll
    for (int e = 0; e < NE; ++e) l[e] += src[e];
  }
#pragma unroll
  for (int e = 0; e < NE; ++e) out[(size_t)row * NE + e] = l[e];

  float m = l[0];
#pragma unroll
  for (int e = 1; e < NE; ++e) m = fmaxf(m, l[e]);
  float p[NE], s = 0.f;
#pragma unroll
  for (int e = 0; e < NE; ++e) {
    p[e] = expf(l[e] - m);
    s += p[e];
  }
  float inv = 1.f / s;

  float v0 = -1.f, v1 = -1.f;
  int i0 = 0, i1 = 0;
#pragma unroll
  for (int e = 0; e < NE; ++e) {
    float pe = p[e];
    if (pe > v0) {
      v1 = v0; i1 = i0;
      v0 = pe; i0 = e;
    } else if (pe > v1) {
      v1 = pe; i1 = e;
    }
  }
  size_t wbase = (size_t)NROWS * NE + (size_t)row * 2;
  out[wbase] = v0 * inv;
  out[wbase + 1] = v1 * inv;
  size_t ibase = (size_t)NROWS * NE + (size_t)NROWS * 2 + (size_t)row * 2;
  out[ibase] = (float)i0;
  out[ibase + 1] = (float)i1;
}

extern "C" void kernel_launch(void* const* d_in, const int* in_sizes, int n_in,
                              void* d_out, int out_size, void* d_ws,
                              size_t ws_size, hipStream_t stream) {
  const float* X = (const float*)d_in[0];
  const float* W1 = (const float*)d_in[1];
  const float* b1 = (const float*)d_in[2];
  const float* W2 = (const float*)d_in[3];
  const float* b2 = (const float*)d_in[4];
  float* out = (float*)d_out;

  // ws: pl 2MB (at 0) | W1s 8MB (at +4MB)
  float* pl = (float*)d_ws;
  f16* W1s = (f16*)((char*)d_ws + (size_t)4 * 1024 * 1024);

  // allow 128 KiB dynamic LDS (non-stream runtime call; capture-safe)
  (void)hipFuncSetAttribute((const void*)router_mfma,
                            hipFuncAttributeMaxDynamicSharedMemorySize, 131072);

  hipLaunchKernelGGL(prep_w1, dim3(256), dim3(256), 0, stream, W1, W1s);
  hipLaunchKernelGGL(router_mfma, dim3(256), dim3(512), 131072, stream, X, W1s,
                     b1, W2, pl);
  hipLaunchKernelGGL(router_finalize, dim3(NROWS / 256), dim3(256), 0, stream,
                     pl, b2, out);
}